// Round 12
// baseline (579.137 us; speedup 1.0000x reference)
//
#include <hip/hip_runtime.h>
#include <hip/hip_bf16.h>

typedef unsigned short ushort_t;
typedef unsigned int uint_t;

typedef __bf16 bf16x8 __attribute__((ext_vector_type(8)));
typedef float f32x4 __attribute__((ext_vector_type(4)));
typedef float f32x16 __attribute__((ext_vector_type(16)));

#define NPTS (1 << 20)

// ---- ws layout (ushort units) ----
// Weights stored as 32x32x16 MFMA A-fragments of W^T: tile = 32 out-cols (m)
// x 16 k; lane l: m = l&31, k = (l>>5)*8 + j. Tile order [kt][mt(8)].
#define OFF_FLAG 0        // uint flag: 1 = inputs bf16, 0 = fp32
#define OFF_B0   16
#define OFF_B1   272
#define OFF_B2   528
#define OFF_B3   784
#define OFF_BSIG 1040
#define OFF_BRGB 1041
#define OFF_W0   1056     // K=64 (47 padded): 4 kt x 8 mt = 32 tiles * 512
#define OFF_W1   17440    // K=256: 16 kt x 8 mt = 128 tiles * 512
#define OFF_W2   82976
#define OFF_W3   148512
#define OFF_WH   214048   // head: 16 kt x 1 mt (cols rgb0,rgb1,rgb2,sig,0..)
#define OFF_PL   222240   // transposed planes [plane][pos(16384)][rank(8)]

__device__ __forceinline__ float bf2f(ushort_t u) {
  union { uint_t i; float f; } c; c.i = ((uint_t)u) << 16; return c.f;
}
__device__ __forceinline__ ushort_t f2bf(float f) {
  union { float f; uint_t i; } c; c.f = f;
  uint_t x = c.i;
  return (ushort_t)((x + 0x7fffu + ((x >> 16) & 1u)) >> 16);
}
__device__ __forceinline__ uint_t pk2bf(float a, float b) {
  __hip_bfloat162 h = __float22bfloat162_rn(float2{a, b});
  union { __hip_bfloat162 h; uint_t u; } c; c.h = h; return c.u;
}
__device__ __forceinline__ float ldf(const void* p, long i, int isbf) {
  return isbf ? bf2f(((const ushort_t*)p)[i]) : ((const float*)p)[i];
}
__device__ __forceinline__ ushort_t ldbf(const void* p, long i, int isbf) {
  return isbf ? ((const ushort_t*)p)[i] : f2bf(((const float*)p)[i]);
}
__device__ __forceinline__ void stf(void* p, long i, int isbf, float v) {
  if (isbf) ((ushort_t*)p)[i] = f2bf(v);
  else      ((float*)p)[i] = v;
}

// Activation LDS layout = 32x32x16 B-fragment native (64 points = 2 n-tiles):
// element (point p, col k) -> frag(ntile=p>>5, kt=k>>4), lane = ((k>>3)&1)*32
// + (p&31), j = k&7.  frag stride 512 ushorts, ntile stride 8192.
__device__ __forceinline__ int fragaddr(int p, int k) {
  return ((p >> 5) << 13) + ((k >> 4) << 9) + (((k >> 3) & 1) << 8)
       + ((p & 31) << 3) + (k & 7);
}

union U { uint4 u; bf16x8 v; };

// ------------------------------------------------------------------
__global__ void sniff_dtype(const void* __restrict__ f, ushort_t* __restrict__ ws) {
  __shared__ int s_cnt;
  if (threadIdx.x == 0) s_cnt = 0;
  __syncthreads();
  const ushort_t* u = (const ushort_t*)f;
  int c = 0;
  for (int j = 0; j < 4; ++j) {
    ushort_t v = u[(threadIdx.x * 4 + j) * 2];
    int e = (v >> 7) & 0xFF;
    if (e > 100 && e < 140) ++c;
  }
  atomicAdd(&s_cnt, c);
  __syncthreads();
  if (threadIdx.x == 0) ((uint_t*)ws)[0] = (s_cnt >= 160) ? 1u : 0u;
}

__global__ void prep_bias(const void* __restrict__ b0, const void* __restrict__ b1,
                          const void* __restrict__ b2, const void* __restrict__ b3,
                          const void* __restrict__ bsig, const void* __restrict__ brgb,
                          ushort_t* __restrict__ ws) {
  const int isbf = (int)((const uint_t*)ws)[0];
  int i = threadIdx.x;
  ws[OFF_B0 + i] = ldbf(b0, i, isbf);
  ws[OFF_B1 + i] = ldbf(b1, i, isbf);
  ws[OFF_B2 + i] = ldbf(b2, i, isbf);
  ws[OFF_B3 + i] = ldbf(b3, i, isbf);
  if (i == 0) ws[OFF_BSIG] = ldbf(bsig, 0, isbf);
  if (i < 3) ws[OFF_BRGB + i] = ldbf(brgb, i, isbf);
}

// weights -> 32x32x16 A-frags of W^T, tile order [kt][mt]
__global__ void prep_weights(const void* __restrict__ W0,
                             const void* __restrict__ W1,
                             const void* __restrict__ W2,
                             const void* __restrict__ W3,
                             const void* __restrict__ Wsig,
                             const void* __restrict__ Wrgb,
                             ushort_t* __restrict__ ws) {
  const int isbf = (int)((const uint_t*)ws)[0];
  int t = blockIdx.x * 256 + threadIdx.x;   // 432 tiles * 64 lanes = 27648
  if (t >= 432 * 64) return;
  int lane = t & 63;
  int tile = t >> 6;
  const void* src = nullptr;
  ushort_t* dst;
  int local, Ksrc = 256;
  bool head = false;
  if (tile < 32) { local = tile; src = W0; Ksrc = 47; dst = ws + OFF_W0 + (size_t)local * 512; }
  else if (tile < 160) { local = tile - 32;  src = W1; dst = ws + OFF_W1 + (size_t)local * 512; }
  else if (tile < 288) { local = tile - 160; src = W2; dst = ws + OFF_W2 + (size_t)local * 512; }
  else if (tile < 416) { local = tile - 288; src = W3; dst = ws + OFF_W3 + (size_t)local * 512; }
  else { local = tile - 416; head = true; dst = ws + OFF_WH + (size_t)local * 512; }
  int kt = head ? local : (local >> 3);
  int mt = head ? 0 : (local & 7);
  int n = mt * 32 + (lane & 31);         // out-col (A-frag m)
  int kb = kt * 16 + (lane >> 5) * 8;    // k base
  for (int j = 0; j < 8; ++j) {
    int k = kb + j;
    ushort_t v = 0;
    if (head) {
      if (n < 3) v = ldbf(Wrgb, (long)k * 3 + n, isbf);
      else if (n == 3) v = ldbf(Wsig, k, isbf);
    } else if (k < Ksrc) {
      v = ldbf(src, (long)k * 256 + n, isbf);
    }
    dst[lane * 8 + j] = v;
  }
}

__global__ void prep_planes(const void* __restrict__ fxy,
                            const void* __restrict__ fxz,
                            const void* __restrict__ fyz,
                            ushort_t* __restrict__ ws) {
  const int isbf = (int)((const uint_t*)ws)[0];
  int t = blockIdx.x * 256 + threadIdx.x;   // 3*16384 = 49152
  int plane = t >> 14, pos = t & 16383;
  const void* src = (plane == 0) ? fxy : (plane == 1) ? fxz : fyz;
  ushort_t* d = ws + OFF_PL + (size_t)plane * 131072 + (size_t)pos * 8;
  for (int r = 0; r < 8; ++r) d[r] = ldbf(src, (long)r * 16384 + pos, isbf);
}

// ------------------------------------------------------------------
// main: block = 256 thr / 4 waves / 64 points, 3 blocks/CU
// (__launch_bounds__(256,3) -> ~168 regs/wave; 12 waves/CU).
// Wave w: out-cols [w*64, w*64+64) (2 m-tiles) x all 64 points (2
// n-tiles): acc[2][2] f32x16 = 64 AGPRs; arch regs ~100.
// Round-11 evidence: at 2 blocks/CU the two blocks phase-lock on
// barriers -> ~50% of each round is stall despite matrix+LDS pipes
// only ~50% busy. P=64 keeps L2 weight traffic (425 KB/block-pass,
// 6.9 GB total ~= 200 us) under the 222 us MFMA floor while tripling
// independent blocks per CU.
// A-prefetch: distance-4 same-slot rotation — use a[j] (tile g*4+j),
// then reload a[j] <- tile (g+1)*4+j. Peeled last group reloads from
// the NEXT layer's tiles j=0..3 (no cold start). Precondition:
// a[0..3] = this layer's tiles 0..3.
// ------------------------------------------------------------------
template <int KT>
__device__ __forceinline__ void mlp_layer(ushort_t* s_act,
                                          const ushort_t* __restrict__ wsW,
                                          const ushort_t* __restrict__ nextW,
                                          const ushort_t* __restrict__ bias,
                                          int w, int lane, U (&a)[4][2]) {
  f32x16 acc[2][2] = {};
  const int p31 = lane & 31;
  const int q2 = lane >> 5;
  const ushort_t* bptr = s_act + lane * 8;                  // + d*8192 + kt*512
  const ushort_t* aptr = wsW + w * 1024 + lane * 8;         // + kt*4096 + mi*512
  const ushort_t* nptr = nextW + w * 1024 + lane * 8;
  U b[2][2];
#pragma unroll
  for (int d = 0; d < 2; ++d) b[0][d].u = *(const uint4*)(bptr + d * 8192);
  // main groups: kt = 0 .. KT-5
#pragma unroll 1
  for (int g = 0; g < KT / 4 - 1; ++g) {
    const ushort_t* ag = aptr + g * 16384;
    const ushort_t* bg = bptr + g * 2048;
#pragma unroll
    for (int j = 0; j < 4; ++j) {
      // B prefetch kt+1 (j=3 rolls into next group's slot 0)
#pragma unroll
      for (int d = 0; d < 2; ++d)
        b[(j + 1) & 1][d].u = *(const uint4*)(bg + (j + 1) * 512 + d * 8192);
#pragma unroll
      for (int mi = 0; mi < 2; ++mi)
#pragma unroll
        for (int d = 0; d < 2; ++d)
          acc[mi][d] = __builtin_amdgcn_mfma_f32_32x32x16_bf16(a[j][mi].v, b[j & 1][d].v, acc[mi][d], 0, 0, 0);
      // A reload same slot, tile kt+4 (distance 4)
#pragma unroll
      for (int mi = 0; mi < 2; ++mi)
        a[j][mi].u = *(const uint4*)(ag + 16384 + j * 4096 + mi * 512);
    }
  }
  // peeled last group: kt = KT-4 .. KT-1; A reloads from next layer
  {
    const ushort_t* bg = bptr + (KT / 4 - 1) * 2048;
#pragma unroll
    for (int j = 0; j < 4; ++j) {
      if (j < 3) {
#pragma unroll
        for (int d = 0; d < 2; ++d)
          b[(j + 1) & 1][d].u = *(const uint4*)(bg + (j + 1) * 512 + d * 8192);
      }
#pragma unroll
      for (int mi = 0; mi < 2; ++mi)
#pragma unroll
        for (int d = 0; d < 2; ++d)
          acc[mi][d] = __builtin_amdgcn_mfma_f32_32x32x16_bf16(a[j][mi].v, b[j & 1][d].v, acc[mi][d], 0, 0, 0);
#pragma unroll
      for (int mi = 0; mi < 2; ++mi)
        a[j][mi].u = *(const uint4*)(nptr + j * 4096 + mi * 512);
    }
  }
  __syncthreads();   // all waves done reading act
  // D: lane -> point p31 (in n-tile d); reg quad rq = 4 consecutive cols
  // col = w*64 + mi*32 + rq*8 + q2*4 + {0..3}
  ushort_t* wbase = s_act + w * 2048 + p31 * 8 + q2 * 4;
#pragma unroll
  for (int mi = 0; mi < 2; ++mi) {
#pragma unroll
    for (int rq = 0; rq < 4; ++rq) {
      int col0 = w * 64 + mi * 32 + rq * 8 + q2 * 4;
      ushort4 bb = *(const ushort4*)(bias + col0);
      float bf0 = bf2f(bb.x), bf1 = bf2f(bb.y), bf2v = bf2f(bb.z), bf3 = bf2f(bb.w);
#pragma unroll
      for (int d = 0; d < 2; ++d) {
        const f32x16& A = acc[mi][d];
        float v0 = fmaxf(A[rq * 4 + 0] + bf0, 0.0f);
        float v1 = fmaxf(A[rq * 4 + 1] + bf1, 0.0f);
        float v2 = fmaxf(A[rq * 4 + 2] + bf2v, 0.0f);
        float v3 = fmaxf(A[rq * 4 + 3] + bf3, 0.0f);
        uint2 pk; pk.x = pk2bf(v0, v1); pk.y = pk2bf(v2, v3);
        *(uint2*)(wbase + d * 8192 + mi * 1024 + (rq >> 1) * 512 + (rq & 1) * 256) = pk;
      }
    }
  }
  __syncthreads();   // act ready for next layer
}

__global__ __launch_bounds__(256, 3)
void tensorf_main(const void* __restrict__ x,
                  const ushort_t* __restrict__ ws,
                  void* __restrict__ out) {
  __shared__ ushort_t s_act[2 * 16 * 512];   // 32 KB frag-native act (64 pts)
  const int isbf = (int)((const uint_t*)ws)[0];
  const int tid = threadIdx.x;
  const int lane = tid & 63;
  const int wid = tid >> 6;        // 0..3
  const int blk = blockIdx.x;

  // Issue layer-0 A-prefetch (tiles 0..3) FIRST: latency hides under Phase A.
  U a[4][2];
  {
    const ushort_t* a0 = ws + OFF_W0 + wid * 1024 + lane * 8;
#pragma unroll
    for (int t = 0; t < 4; ++t)
#pragma unroll
      for (int mi = 0; mi < 2; ++mi)
        a[t][mi].u = *(const uint4*)(a0 + t * 4096 + mi * 512);
  }

  // ---- Phase A: features + PE into frag layout, cols 0..63 ----
  // 4 threads per point: s=0 gather+x; s=1: lvl 0,1; s=2: lvl 2,3; s=3: lvl 4,5+pad
  {
    int pl = tid >> 2;            // 0..63
    int s = tid & 3;
    long p = (long)blk * 64 + pl;
    float x0 = ldf(x, p * 3 + 0, isbf);
    float x1 = ldf(x, p * 3 + 1, isbf);
    float x2 = ldf(x, p * 3 + 2, isbf);
    float fx[3] = { x0, x1, x2 };
    if (s == 0) {
      int ix = (int)(((x0 + 1.0f) * 0.5f) * 127.0f);
      int iy = (int)(((x1 + 1.0f) * 0.5f) * 127.0f);
      int iz = (int)(((x2 + 1.0f) * 0.5f) * 127.0f);
      ix = ix < 0 ? 0 : (ix > 127 ? 127 : ix);
      iy = iy < 0 ? 0 : (iy > 127 ? 127 : iy);
      iz = iz < 0 ? 0 : (iz > 127 ? 127 : iz);
      union { uint4 u; ushort_t s[8]; } a4, b4, c4;
      a4.u = *(const uint4*)(ws + OFF_PL + (size_t)(iy * 128 + ix) * 8);
      b4.u = *(const uint4*)(ws + OFF_PL + 131072 + (size_t)(iz * 128 + ix) * 8);
      c4.u = *(const uint4*)(ws + OFF_PL + 262144 + (size_t)(iz * 128 + iy) * 8);
      union { uint4 u; uint_t w[4]; } f;
#pragma unroll
      for (int r = 0; r < 8; r += 2) {
        float f0 = bf2f(a4.s[r]) + bf2f(b4.s[r]) + bf2f(c4.s[r]);
        float f1 = bf2f(a4.s[r + 1]) + bf2f(b4.s[r + 1]) + bf2f(c4.s[r + 1]);
        f.w[r >> 1] = pk2bf(f0, f1);
      }
      *(uint4*)(s_act + fragaddr(pl, 0)) = f.u;      // cols 0..7 contiguous
      *(uint_t*)(s_act + fragaddr(pl, 8)) = pk2bf(x0, x1);
      s_act[fragaddr(pl, 10)] = f2bf(x2);
    } else if (s == 3) {
#pragma unroll
      for (int l = 4; l < 6; ++l) {
        float fr = (float)(1 << l);
        int k0 = 11 + l * 6;
#pragma unroll
        for (int dd = 0; dd < 3; ++dd) {
          float ang = fx[dd] * fr;
          s_act[fragaddr(pl, k0 + dd)]     = f2bf(__sinf(ang));
          s_act[fragaddr(pl, k0 + 3 + dd)] = f2bf(__cosf(ang));
        }
      }
      s_act[fragaddr(pl, 47)] = 0;
      *(uint4*)(s_act + fragaddr(pl, 48)) = uint4{0, 0, 0, 0};
      *(uint4*)(s_act + fragaddr(pl, 56)) = uint4{0, 0, 0, 0};
    } else {
#pragma unroll
      for (int li = 0; li < 2; ++li) {
        int l = (s - 1) * 2 + li;
        float fr = (float)(1 << l);
        int k0 = 11 + l * 6;
#pragma unroll
        for (int dd = 0; dd < 3; ++dd) {
          float ang = fx[dd] * fr;
          s_act[fragaddr(pl, k0 + dd)]     = f2bf(__sinf(ang));
          s_act[fragaddr(pl, k0 + 3 + dd)] = f2bf(__cosf(ang));
        }
      }
    }
  }
  __syncthreads();

  mlp_layer<4>(s_act,  ws + OFF_W0, ws + OFF_W1, ws + OFF_B0, wid, lane, a);
  mlp_layer<16>(s_act, ws + OFF_W1, ws + OFF_W2, ws + OFF_B1, wid, lane, a);
  mlp_layer<16>(s_act, ws + OFF_W2, ws + OFF_W3, ws + OFF_B2, wid, lane, a);
  mlp_layer<16>(s_act, ws + OFF_W3, ws + OFF_WH, ws + OFF_B3, wid, lane, a);

  // ---- head: D = Wh^T(32x256, cols 0..3 real) x Act^T; waves 0,1 ----
  if (wid < 2) {
    f32x16 acc = {};
    const int p31 = lane & 31;
    const int q2 = lane >> 5;
    const ushort_t* hb = s_act + wid * 8192 + lane * 8;
    const ushort_t* wh = ws + OFF_WH + lane * 8;
#pragma unroll 4
    for (int kt = 0; kt < 16; ++kt) {
      union { uint4 u; bf16x8 v; } ta, tb;
      ta.u = *(const uint4*)(wh + kt * 512);
      tb.u = *(const uint4*)(hb + kt * 512);
      acc = __builtin_amdgcn_mfma_f32_32x32x16_bf16(ta.v, tb.v, acc, 0, 0, 0);
    }
    if (q2 == 0) {   // regs 0..3 = cols 0..3 = rgb0, rgb1, rgb2, sigma
      long pp = (long)blk * 64 + wid * 32 + p31;
      float br0 = bf2f(ws[OFF_BRGB + 0]), br1 = bf2f(ws[OFF_BRGB + 1]), br2 = bf2f(ws[OFF_BRGB + 2]);
      float bs = bf2f(ws[OFF_BSIG]);
      float z0 = acc[0] + br0, z1 = acc[1] + br1, z2 = acc[2] + br2;
      stf(out, pp * 3 + 0, isbf, 1.0f / (1.0f + __expf(-z0)));
      stf(out, pp * 3 + 1, isbf, 1.0f / (1.0f + __expf(-z1)));
      stf(out, pp * 3 + 2, isbf, 1.0f / (1.0f + __expf(-z2)));
      float zs = acc[3] + bs;
      float sp = (zs > 20.0f) ? zs : __logf(1.0f + __expf(zs));
      stf(out, (long)3 * NPTS + pp, isbf, sp);
    }
  }
}

extern "C" void kernel_launch(void* const* d_in, const int* in_sizes, int n_in,
                              void* d_out, int out_size, void* d_ws, size_t ws_size,
                              hipStream_t stream) {
  const void* x    = d_in[0];
  const void* fxy  = d_in[1];
  const void* fxz  = d_in[2];
  const void* fyz  = d_in[3];
  const void* W0   = d_in[4];
  const void* b0   = d_in[5];
  const void* W1   = d_in[6];
  const void* b1   = d_in[7];
  const void* W2   = d_in[8];
  const void* b2   = d_in[9];
  const void* W3   = d_in[10];
  const void* b3   = d_in[11];
  const void* Wsig = d_in[12];
  const void* bsig = d_in[13];
  const void* Wrgb = d_in[14];
  const void* brgb = d_in[15];
  ushort_t* ws = (ushort_t*)d_ws;

  hipLaunchKernelGGL(sniff_dtype, dim3(1), dim3(64), 0, stream, fxy, ws);
  hipLaunchKernelGGL(prep_bias, dim3(1), dim3(256), 0, stream,
                     b0, b1, b2, b3, bsig, brgb, ws);
  hipLaunchKernelGGL(prep_weights, dim3(108), dim3(256), 0, stream,
                     W0, W1, W2, W3, Wsig, Wrgb, ws);
  hipLaunchKernelGGL(prep_planes, dim3(192), dim3(256), 0, stream,
                     fxy, fxz, fyz, ws);
  hipLaunchKernelGGL(tensorf_main, dim3(16384), dim3(256), 0, stream,
                     x, ws, d_out);
}